// Round 1
// baseline (66.200 us; speedup 1.0000x reference)
//
#include <hip/hip_runtime.h>
#include <math.h>

#define G 24
#define NPTS (G * G)      // 576
#define ROWS (NPTS + 1)   // 577, output edge
#define HD 64
#define BH (8 * 12)       // 96
#define EPSF 0.1f
#define COEFF 576.0f
#define BSHIFT 6.3543700408f  // log(575)

__global__ __launch_bounds__(256) void gaussian_augment_kernel(
    const float* __restrict__ q,
    const float* __restrict__ Wv,
    const float* __restrict__ bv,
    const float* __restrict__ Wa,
    const float* __restrict__ ba,
    float* __restrict__ out)
{
    const int gid = blockIdx.x;            // 0 .. BH*ROWS-1
    const int bh  = gid / ROWS;
    const int r   = gid - bh * ROWS;       // output row index 0..576
    const int tid = threadIdx.x;

    float* orow = out + ((size_t)bh * ROWS + r) * ROWS;

    if (r == 0) {
        // prefix (padding) row: all zeros
        for (int c = tid; c < ROWS; c += 256) orow[c] = 0.0f;
        return;
    }

    __shared__ float s_p[3];
    __shared__ float ex0[G];
    __shared__ float ex1[G];

    // ---- 3 dot products over head_dim=64, done by wave 0 ----
    if (tid < 64) {
        const float* qrow = q + ((size_t)bh * ROWS + r) * HD;  // qs[n] = q[r], r=n+1
        float qv = qrow[tid];
        float p0 = qv * Wv[tid * 2 + 0];
        float p1 = qv * Wv[tid * 2 + 1];
        float p2 = qv * Wa[tid];
        #pragma unroll
        for (int off = 32; off >= 1; off >>= 1) {
            p0 += __shfl_xor(p0, off);
            p1 += __shfl_xor(p1, off);
            p2 += __shfl_xor(p2, off);
        }
        if (tid == 0) { s_p[0] = p0; s_p[1] = p1; s_p[2] = p2; }
    }
    __syncthreads();

    // ---- per-row params (computed redundantly per thread; cheap) ----
    const float x0 = s_p[0] + bv[0] - BSHIFT;
    const float x1 = s_p[1] + bv[1] - BSHIFT;
    const float xa = s_p[2] + ba[0];

    const float var0 = COEFF / (1.0f + expf(-x0));
    const float var1 = COEFF / (1.0f + expf(-x1));
    const float inv0 = 1.0f / (var0 + EPSF);
    const float inv1 = 1.0f / (var1 + EPSF);
    // softplus, overflow-safe
    const float alpha = fmaxf(xa, 0.0f) + log1pf(expf(-fabsf(xa)));

    // ---- 24-entry exp tables; alpha folded into ex0 ----
    if (tid < G) {
        float t = (float)tid;
        ex0[tid] = alpha * expf(-0.5f * t * t * inv0);
    } else if (tid < 2 * G) {
        float t = (float)(tid - G);
        ex1[tid - G] = expf(-0.5f * t * t * inv1);
    }
    __syncthreads();

    // ---- write one output row of 577 (col 0 = padding zero) ----
    const int n  = r - 1;
    const int in = n / G;
    const int jn = n - in * G;

    for (int c = tid; c < ROWS; c += 256) {
        float v = 0.0f;
        if (c > 0) {
            const int m  = c - 1;
            const int im = m / G;
            const int jm = m - im * G;
            const int di = (in > im) ? (in - im) : (im - in);
            const int dj = (jn > jm) ? (jn - jm) : (jm - jn);
            v = ex0[di] * ex1[dj];
        }
        orow[c] = v;
    }
}

extern "C" void kernel_launch(void* const* d_in, const int* in_sizes, int n_in,
                              void* d_out, int out_size, void* d_ws, size_t ws_size,
                              hipStream_t stream) {
    const float* q  = (const float*)d_in[0];
    const float* Wv = (const float*)d_in[1];
    const float* bv = (const float*)d_in[2];
    const float* Wa = (const float*)d_in[3];
    const float* ba = (const float*)d_in[4];
    float* out = (float*)d_out;

    const int grid = BH * ROWS;  // 55392 blocks, one per output row
    gaussian_augment_kernel<<<grid, 256, 0, stream>>>(q, Wv, bv, Wa, ba, out);
}

// Round 3
// 43.107 us; speedup vs baseline: 1.5357x; 1.5357x over previous
//
#include <hip/hip_runtime.h>
#include <math.h>

#define G 24
#define NPTS (G * G)      // 576
#define ROWS (NPTS + 1)   // 577
#define HD 64
#define BH (8 * 12)       // 96
#define EPSF 0.1f
#define COEFF 576.0f
#define BSHIFT 6.3543700408f  // log(575)
#define RPB 8                 // rows per block
#define BPI ((ROWS + RPB - 1) / RPB)  // 73 blocks per image

typedef float f32x4 __attribute__((ext_vector_type(4)));

__global__ __launch_bounds__(256) void gaussian_augment_kernel(
    const float* __restrict__ q,
    const float* __restrict__ Wv,
    const float* __restrict__ bv,
    const float* __restrict__ Wa,
    const float* __restrict__ ba,
    float* __restrict__ out)
{
    const int bh  = blockIdx.x / BPI;
    const int blk = blockIdx.x - bh * BPI;
    const int r0  = blk * RPB;
    const int Ract = min(RPB, ROWS - r0);
    const int tid = threadIdx.x;

    __shared__ float s_dot[RPB][3];
    __shared__ float s_par[RPB][3];
    __shared__ float s_ex0[RPB][G];
    __shared__ float s_ex1[RPB][G];
    __shared__ __align__(16) float s_row[RPB * ROWS + 4];

    // ---- Phase 1: dot products (3 per row) over head_dim=64 ----
    const int wave = tid >> 6;
    const int lane = tid & 63;
    #pragma unroll
    for (int pass = 0; pass < 2; ++pass) {
        const int rr = wave + 4 * pass;
        if (rr < Ract) {
            const int r = r0 + rr;
            const float* qrow = q + ((size_t)bh * ROWS + r) * HD;
            const float qv = qrow[lane];
            float p0 = qv * Wv[2 * lane + 0];
            float p1 = qv * Wv[2 * lane + 1];
            float p2 = qv * Wa[lane];
            #pragma unroll
            for (int off = 32; off >= 1; off >>= 1) {
                p0 += __shfl_xor(p0, off);
                p1 += __shfl_xor(p1, off);
                p2 += __shfl_xor(p2, off);
            }
            if (lane == 0) {
                s_dot[rr][0] = p0;
                s_dot[rr][1] = p1;
                s_dot[rr][2] = p2;
            }
        }
    }
    __syncthreads();

    // ---- Phase 2: row params — transcendentals ONCE per row ----
    if (tid < Ract) {
        const int r = r0 + tid;
        const float x0 = s_dot[tid][0] + bv[0] - BSHIFT;
        const float x1 = s_dot[tid][1] + bv[1] - BSHIFT;
        const float xa = s_dot[tid][2] + ba[0];
        const float var0 = COEFF / (1.0f + expf(-x0));
        const float var1 = COEFF / (1.0f + expf(-x1));
        s_par[tid][0] = 1.0f / (var0 + EPSF);
        s_par[tid][1] = 1.0f / (var1 + EPSF);
        // softplus (overflow-safe); row 0 is the zero-padding prefix row
        const float alpha = fmaxf(xa, 0.0f) + log1pf(expf(-fabsf(xa)));
        s_par[tid][2] = (r == 0) ? 0.0f : alpha;
    }
    __syncthreads();

    // ---- Phase 3: 48-entry exp tables per row (alpha folded into ex0) ----
    for (int e = tid; e < Ract * 48; e += 256) {
        const int rr = e / 48;
        const int k  = e - rr * 48;
        if (k < G) {
            const float t = (float)k;
            s_ex0[rr][k] = s_par[rr][2] * expf(-0.5f * t * t * s_par[rr][0]);
        } else {
            const float t = (float)(k - G);
            s_ex1[rr][k - G] = expf(-0.5f * t * t * s_par[rr][1]);
        }
    }
    __syncthreads();

    // ---- Phase 4a: fill the contiguous 8-row span in LDS ----
    const size_t base = ((size_t)bh * ROWS + r0) * ROWS;  // first element this block owns
    const size_t S0   = base & ~(size_t)3;                // rounded down to 16B
    const int    off  = (int)(base - S0);                 // 0..3

    for (int rr = 0; rr < Ract; ++rr) {
        const int r = r0 + rr;
        const int n = (r > 0) ? r - 1 : 0;
        const int in_ = n / G;
        const int jn_ = n - in_ * G;
        float* lrow = s_row + off + rr * ROWS;
        for (int c = tid; c < ROWS; c += 256) {
            float v = 0.0f;
            if (c > 0) {
                const int m  = c - 1;
                const int im = m / G;
                const int jm = m - im * G;
                const int di = (in_ > im) ? (in_ - im) : (im - in_);
                const int dj = (jn_ > jm) ? (jn_ - jm) : (jm - jn_);
                v = s_ex0[rr][di] * s_ex1[rr][dj];
            }
            lrow[c] = v;
        }
    }
    __syncthreads();

    // ---- Phase 4b: LDS -> global, 16B-aligned non-temporal dwordx4 ----
    const int span = Ract * ROWS;
    const size_t E = base + span;                 // exclusive end
    const int nch  = (int)((E - S0 + 3) >> 2);    // # of float4 chunks

    for (int idx = tid; idx < nch; idx += 256) {
        const size_t g0 = S0 + (size_t)4 * idx;
        if (g0 >= base && g0 + 4 <= E) {
            const f32x4 v = *(const f32x4*)&s_row[4 * idx];
            __builtin_nontemporal_store(v, (f32x4*)(out + g0));
        } else {
            // boundary chunk: only store lanes inside [base, E)
            #pragma unroll
            for (int t = 0; t < 4; ++t) {
                const size_t g = g0 + t;
                if (g >= base && g < E) out[g] = s_row[4 * idx + t];
            }
        }
    }
}

extern "C" void kernel_launch(void* const* d_in, const int* in_sizes, int n_in,
                              void* d_out, int out_size, void* d_ws, size_t ws_size,
                              hipStream_t stream) {
    const float* q  = (const float*)d_in[0];
    const float* Wv = (const float*)d_in[1];
    const float* bv = (const float*)d_in[2];
    const float* Wa = (const float*)d_in[3];
    const float* ba = (const float*)d_in[4];
    float* out = (float*)d_out;

    const int grid = BH * BPI;  // 96 * 73 = 7008 blocks
    gaussian_augment_kernel<<<grid, 256, 0, stream>>>(q, Wv, bv, Wa, ba, out);
}

// Round 4
// 37.183 us; speedup vs baseline: 1.7804x; 1.1593x over previous
//
#include <hip/hip_runtime.h>
#include <math.h>

#define G 24
#define NPTS (G * G)      // 576
#define ROWS (NPTS + 1)   // 577
#define HD 64
#define BH (8 * 12)       // 96
#define EPSF 0.1f
#define COEFF 576.0f
#define BSHIFT 6.3543700408f  // log(575)
#define RPB 8                 // rows per block
#define BPI ((ROWS + RPB - 1) / RPB)  // 73 blocks per image

typedef float f32x4 __attribute__((ext_vector_type(4)));

__global__ __launch_bounds__(256) void gaussian_augment_kernel(
    const float* __restrict__ q,
    const float* __restrict__ Wv,
    const float* __restrict__ bv,
    const float* __restrict__ Wa,
    const float* __restrict__ ba,
    float* __restrict__ out)
{
    const int bh  = blockIdx.x / BPI;
    const int blk = blockIdx.x - bh * BPI;
    const int r0  = blk * RPB;
    const int Ract = min(RPB, ROWS - r0);
    const int tid = threadIdx.x;

    __shared__ float s_dot[RPB][3];
    __shared__ float s_par[RPB][3];
    // ABSOLUTE-indexed tables: s_ex0[rr][im] = alpha*exp(-.5*(in-im)^2*inv0)
    __shared__ float s_ex0[RPB][G];
    __shared__ float s_ex1[RPB][G];

    // ---- Phase 1: dot products (3 per row) over head_dim=64 ----
    const int wave = tid >> 6;
    const int lane = tid & 63;
    #pragma unroll
    for (int pass = 0; pass < 2; ++pass) {
        const int rr = wave + 4 * pass;
        if (rr < Ract) {
            const int r = r0 + rr;
            const float* qrow = q + ((size_t)bh * ROWS + r) * HD;
            const float qv = qrow[lane];
            float p0 = qv * Wv[2 * lane + 0];
            float p1 = qv * Wv[2 * lane + 1];
            float p2 = qv * Wa[lane];
            #pragma unroll
            for (int off = 32; off >= 1; off >>= 1) {
                p0 += __shfl_xor(p0, off);
                p1 += __shfl_xor(p1, off);
                p2 += __shfl_xor(p2, off);
            }
            if (lane == 0) {
                s_dot[rr][0] = p0;
                s_dot[rr][1] = p1;
                s_dot[rr][2] = p2;
            }
        }
    }
    __syncthreads();

    // ---- Phase 2: row params — transcendentals ONCE per row ----
    if (tid < Ract) {
        const int r = r0 + tid;
        const float x0 = s_dot[tid][0] + bv[0] - BSHIFT;
        const float x1 = s_dot[tid][1] + bv[1] - BSHIFT;
        const float xa = s_dot[tid][2] + ba[0];
        const float var0 = COEFF / (1.0f + expf(-x0));
        const float var1 = COEFF / (1.0f + expf(-x1));
        s_par[tid][0] = 1.0f / (var0 + EPSF);
        s_par[tid][1] = 1.0f / (var1 + EPSF);
        // softplus (overflow-safe); row 0 is the zero-padding prefix row
        const float alpha = fmaxf(xa, 0.0f) + log1pf(expf(-fabsf(xa)));
        s_par[tid][2] = (r == 0) ? 0.0f : alpha;
    }
    __syncthreads();

    // ---- Phase 3: 48-entry ABSOLUTE exp tables per row ----
    for (int e = tid; e < Ract * 48; e += 256) {
        const int rr = e / 48;
        const int k  = e - rr * 48;                 // 0..47
        const int r  = r0 + rr;
        const int n  = (r > 0) ? r - 1 : 0;
        const int in_ = n / G;
        const int jn_ = n - in_ * G;
        if (k < G) {
            const float t = (float)(in_ - k);       // im = k
            s_ex0[rr][k] = s_par[rr][2] * expf(-0.5f * t * t * s_par[rr][0]);
        } else {
            const float t = (float)(jn_ - (k - G)); // jm = k-G
            s_ex1[rr][k - G] = expf(-0.5f * t * t * s_par[rr][1]);
        }
    }
    __syncthreads();

    // ---- Phase 4: direct compute + aligned dwordx4 nt stores ----
    const size_t base = ((size_t)bh * ROWS + r0) * ROWS;  // first owned element
    const int span  = Ract * ROWS;
    const size_t E  = base + span;                        // exclusive end
    const size_t S0 = base & ~(size_t)3;                  // 16B-aligned start
    const int nch   = (int)((E - S0 + 3) >> 2);           // # float4 chunks

    for (int idx = tid; idx < nch; idx += 256) {
        const size_t g0 = S0 + (size_t)4 * idx;
        const int e0 = (int)((long long)g0 - (long long)base);  // may be -3..-1
        float v[4];
        #pragma unroll
        for (int t = 0; t < 4; ++t) {
            const int e = e0 + t;
            float val = 0.0f;
            if (e >= 0 && e < span) {
                const unsigned eu = (unsigned)e;
                const int rr = (int)(eu / 577u);        // magic-mul
                const int c  = e - rr * 577;
                if (c > 0) {
                    const unsigned m = (unsigned)(c - 1);
                    const int im = (int)(m / 24u);      // magic-mul
                    const int jm = (int)m - im * 24;
                    val = s_ex0[rr][im] * s_ex1[rr][jm];
                }
            }
            v[t] = val;
        }
        if (e0 >= 0 && e0 + 4 <= span) {
            f32x4 pk = { v[0], v[1], v[2], v[3] };
            __builtin_nontemporal_store(pk, (f32x4*)(out + g0));
        } else {
            #pragma unroll
            for (int t = 0; t < 4; ++t) {
                const int e = e0 + t;
                if (e >= 0 && e < span) out[g0 + t] = v[t];
            }
        }
    }
}

extern "C" void kernel_launch(void* const* d_in, const int* in_sizes, int n_in,
                              void* d_out, int out_size, void* d_ws, size_t ws_size,
                              hipStream_t stream) {
    const float* q  = (const float*)d_in[0];
    const float* Wv = (const float*)d_in[1];
    const float* bv = (const float*)d_in[2];
    const float* Wa = (const float*)d_in[3];
    const float* ba = (const float*)d_in[4];
    float* out = (float*)d_out;

    const int grid = BH * BPI;  // 96 * 73 = 7008 blocks
    gaussian_augment_kernel<<<grid, 256, 0, stream>>>(q, Wv, bv, Wa, ba, out);
}